// Round 1
// baseline (520.518 us; speedup 1.0000x reference)
//
#include <hip/hip_runtime.h>
#include <hip/hip_bf16.h>

// ---------------- helpers ----------------
using short8 = __attribute__((ext_vector_type(8))) short;
using f32x4  = __attribute__((ext_vector_type(4))) float;

__device__ __forceinline__ float bf2f(unsigned short h) {
  union { unsigned int u; float f; } x; x.u = ((unsigned int)h) << 16; return x.f;
}
__device__ __forceinline__ unsigned short f2bf(float f) {
  union { float f; unsigned int u; } x; x.f = f;
  unsigned int r = (x.u + 0x7fffu + ((x.u >> 16) & 1u)) >> 16;
  return (unsigned short)r;
}

__device__ __forceinline__ void gld_lds16(const short* gp, short* lp) {
  __builtin_amdgcn_global_load_lds((const __attribute__((address_space(1))) void*)gp,
                                   (__attribute__((address_space(3))) void*)lp, 16, 0, 0);
}

// ---------------- fp32 -> bf16 cast (vectorized) ----------------
__global__ __launch_bounds__(256) void cast_f32_to_bf16(const float4* __restrict__ in,
                                                        short* __restrict__ out, int n4) {
  int i = blockIdx.x * 256 + threadIdx.x;
  if (i >= n4) return;
  float4 f = in[i];
  short4 o;
  o.x = (short)f2bf(f.x); o.y = (short)f2bf(f.y);
  o.z = (short)f2bf(f.z); o.w = (short)f2bf(f.w);
  *(short4*)(out + 4 * (size_t)i) = o;
}

// ---------------- m97-style GEMM: C = A(MxK) * B(NxK)^T ----------------
// MODE 0: fp32 output, row-major ldc
// MODE 1: bf16 output, row-major ldc
// MODE 2: bf16 output transposed with batching: b=row/rpb, s=row%rpb,
//         C[b*tstride + col*ldc + s]
template <int MODE>
__global__ __launch_bounds__(256) void gemm_bt(const short* __restrict__ A,
                                               const short* __restrict__ B,
                                               void* __restrict__ Cv,
                                               int M, int N, int K, int ldc,
                                               float scale, int rpb, long long tstride) {
  __shared__ short lA[128 * 64];
  __shared__ short lB[128 * 64];
  const int tid = threadIdx.x;
  const int w   = tid >> 6;     // wave 0..3
  const int l   = tid & 63;     // lane
  const int wm  = w >> 1, wn = w & 1;
  const long long tm = (long long)blockIdx.y * 128;
  const long long tn = (long long)blockIdx.x * 128;

  f32x4 acc[4][4] = {};

  const int lr  = l >> 3;        // row-in-segment (8 rows / 1KB wave load)
  const int lc  = (l & 7) * 8;   // col offset (elements)
  const int klo = (l >> 4) * 8;  // k offset within 32-chunk for A/B frags
  const int fr  = l & 15;        // m (or n) within 16-tile

  for (int k0 = 0; k0 < K; k0 += 64) {
    // stage 128x64 A-tile and B-tile via global_load_lds (16B/lane)
#pragma unroll
    for (int t = 0; t < 4; ++t) {
      const int seg = w * 4 + t;
      gld_lds16(A + (tm + seg * 8 + lr) * (long long)K + k0 + lc, &lA[seg * 512]);
      gld_lds16(B + (tn + seg * 8 + lr) * (long long)K + k0 + lc, &lB[seg * 512]);
    }
    __syncthreads();
#pragma unroll
    for (int kk = 0; kk < 64; kk += 32) {
      short8 af[4], bfr[4];
#pragma unroll
      for (int i = 0; i < 4; ++i)
        af[i] = *(const short8*)&lA[(wm * 64 + i * 16 + fr) * 64 + kk + klo];
#pragma unroll
      for (int j = 0; j < 4; ++j)
        bfr[j] = *(const short8*)&lB[(wn * 64 + j * 16 + fr) * 64 + kk + klo];
#pragma unroll
      for (int i = 0; i < 4; ++i)
#pragma unroll
        for (int j = 0; j < 4; ++j)
          acc[i][j] = __builtin_amdgcn_mfma_f32_16x16x32_bf16(af[i], bfr[j], acc[i][j], 0, 0, 0);
    }
    __syncthreads();
  }

  // epilogue: C row=(l>>4)*4+r, col=l&15 within each 16x16 tile
  const int rb = (l >> 4) * 4;
#pragma unroll
  for (int i = 0; i < 4; ++i) {
#pragma unroll
    for (int j = 0; j < 4; ++j) {
#pragma unroll
      for (int r = 0; r < 4; ++r) {
        const long long row = tm + wm * 64 + i * 16 + rb + r;
        const long long col = tn + wn * 64 + j * 16 + fr;
        const float v = acc[i][j][r] * scale;
        if (MODE == 0) {
          ((float*)Cv)[row * ldc + col] = v;
        } else if (MODE == 1) {
          ((unsigned short*)Cv)[row * ldc + col] = f2bf(v);
        } else {
          const long long bb = row / rpb, s = row % rpb;
          ((unsigned short*)Cv)[bb * tstride + col * (long long)ldc + s] = f2bf(v);
        }
      }
    }
  }
}

// ---------------- row softmax over 4096 cols, bf16 in/out, fp32 math --------
__global__ __launch_bounds__(256) void softmax4096(const unsigned short* __restrict__ S,
                                                   unsigned short* __restrict__ P,
                                                   float scale) {
  __shared__ float redm[4], reds[4];
  const long long row = blockIdx.x;
  const int tid = threadIdx.x;
  const int w = tid >> 6, l = tid & 63;
  const unsigned short* src = S + row * 4096 + tid * 16;
  short8 r0 = *(const short8*)src;
  short8 r1 = *(const short8*)(src + 8);
  float v[16];
#pragma unroll
  for (int i = 0; i < 8; ++i) v[i] = bf2f((unsigned short)r0[i]) * scale;
#pragma unroll
  for (int i = 0; i < 8; ++i) v[8 + i] = bf2f((unsigned short)r1[i]) * scale;
  float m = v[0];
#pragma unroll
  for (int i = 1; i < 16; ++i) m = fmaxf(m, v[i]);
#pragma unroll
  for (int off = 32; off; off >>= 1) m = fmaxf(m, __shfl_xor(m, off));
  if (l == 0) redm[w] = m;
  __syncthreads();
  m = fmaxf(fmaxf(redm[0], redm[1]), fmaxf(redm[2], redm[3]));
  float sum = 0.f;
#pragma unroll
  for (int i = 0; i < 16; ++i) { v[i] = __expf(v[i] - m); sum += v[i]; }
#pragma unroll
  for (int off = 32; off; off >>= 1) sum += __shfl_xor(sum, off);
  if (l == 0) reds[w] = sum;
  __syncthreads();
  const float inv = 1.0f / (reds[0] + reds[1] + reds[2] + reds[3]);
  short8 o0, o1;
#pragma unroll
  for (int i = 0; i < 8; ++i) o0[i] = (short)f2bf(v[i] * inv);
#pragma unroll
  for (int i = 0; i < 8; ++i) o1[i] = (short)f2bf(v[8 + i] * inv);
  unsigned short* dst = P + row * 4096 + tid * 16;
  *(short8*)dst = o0;
  *(short8*)(dst + 8) = o1;
}

// ---------------- launch ----------------
extern "C" void kernel_launch(void* const* d_in, const int* in_sizes, int n_in,
                              void* d_out, int out_size, void* d_ws, size_t ws_size,
                              hipStream_t stream) {
  const float* x  = (const float*)d_in[0];
  const float* Wq = (const float*)d_in[1];
  const float* Wk = (const float*)d_in[2];
  const float* Wv = (const float*)d_in[3];
  const float* Wo = (const float*)d_in[4];
  float* out = (float*)d_out;

  // ws layout (bytes):
  // [0,16M)   xb      8192x1024 bf16
  // [16M,24M) wq/wk/wv/wo  4 x 1024x1024 bf16
  // [24M,40M) q    [40M,56M) k    [56M,72M) vt[2][1024][4096]   [72M,88M) ao
  // [88M,120M) scores 4096x4096 bf16 (reused per batch)
  char* ws = (char*)d_ws;
  short* xb = (short*)(ws);
  short* wq = (short*)(ws + (16ll << 20));
  short* wk = wq + 1024 * 1024;
  short* wv = wk + 1024 * 1024;
  short* wo = wv + 1024 * 1024;
  short* q  = (short*)(ws + (24ll << 20));
  short* k  = q + 8192ll * 1024;
  short* vt = k + 8192ll * 1024;
  short* ao = vt + 8192ll * 1024;
  short* sc = ao + 8192ll * 1024;

  dim3 blk(256);

  // casts
  cast_f32_to_bf16<<<8192, blk, 0, stream>>>((const float4*)x, xb, 2097152);
  cast_f32_to_bf16<<<1024, blk, 0, stream>>>((const float4*)Wq, wq, 262144);
  cast_f32_to_bf16<<<1024, blk, 0, stream>>>((const float4*)Wk, wk, 262144);
  cast_f32_to_bf16<<<1024, blk, 0, stream>>>((const float4*)Wv, wv, 262144);
  cast_f32_to_bf16<<<1024, blk, 0, stream>>>((const float4*)Wo, wo, 262144);

  // projections: q,k (row-major bf16), v written transposed per batch
  dim3 gp(1024 / 128, 8192 / 128);
  gemm_bt<1><<<gp, blk, 0, stream>>>(xb, wq, q, 8192, 1024, 1024, 1024, 1.f, 0, 0);
  gemm_bt<1><<<gp, blk, 0, stream>>>(xb, wk, k, 8192, 1024, 1024, 1024, 1.f, 0, 0);
  gemm_bt<2><<<gp, blk, 0, stream>>>(xb, wv, vt, 8192, 1024, 1024, 4096, 1.f, 4096,
                                     4096ll * 1024);

  // attention per batch (reuse scores buffer)
  for (int b = 0; b < 2; ++b) {
    short* qb  = q  + (long long)b * 4096 * 1024;
    short* kb  = k  + (long long)b * 4096 * 1024;
    short* vb  = vt + (long long)b * 4096 * 1024;
    short* aob = ao + (long long)b * 4096 * 1024;
    dim3 gs(4096 / 128, 4096 / 128);
    gemm_bt<1><<<gs, blk, 0, stream>>>(qb, kb, sc, 4096, 4096, 1024, 4096, 1.f, 0, 0);
    softmax4096<<<4096, blk, 0, stream>>>((unsigned short*)sc, (unsigned short*)sc,
                                          0.03125f);  // 1/sqrt(1024)
    dim3 gpv(1024 / 128, 4096 / 128);
    gemm_bt<1><<<gpv, blk, 0, stream>>>(sc, vb, aob, 4096, 1024, 4096, 1024, 1.f, 0, 0);
  }

  // output projection, fp32 to d_out
  dim3 go(1024 / 128, 8192 / 128);
  gemm_bt<0><<<go, blk, 0, stream>>>(ao, wo, out, 8192, 1024, 1024, 1024, 1.f, 0, 0);
}

// Round 2
// 426.695 us; speedup vs baseline: 1.2199x; 1.2199x over previous
//
#include <hip/hip_runtime.h>
#include <hip/hip_bf16.h>

// ---------------- helpers ----------------
using short8 = __attribute__((ext_vector_type(8))) short;
using f32x4  = __attribute__((ext_vector_type(4))) float;

__device__ __forceinline__ float bf2f(unsigned short h) {
  union { unsigned int u; float f; } x; x.u = ((unsigned int)h) << 16; return x.f;
}
__device__ __forceinline__ unsigned short f2bf(float f) {
  union { float f; unsigned int u; } x; x.f = f;
  unsigned int r = (x.u + 0x7fffu + ((x.u >> 16) & 1u)) >> 16;
  return (unsigned short)r;
}

__device__ __forceinline__ void gld_lds16(const short* gp, short* lp) {
  __builtin_amdgcn_global_load_lds((const __attribute__((address_space(1))) void*)gp,
                                   (__attribute__((address_space(3))) void*)lp, 16, 0, 0);
}

// ---------------- fp32 -> bf16 cast (vectorized) ----------------
__global__ __launch_bounds__(256) void cast_f32_to_bf16(const float4* __restrict__ in,
                                                        short* __restrict__ out, int n4) {
  int i = blockIdx.x * 256 + threadIdx.x;
  if (i >= n4) return;
  float4 f = in[i];
  short4 o;
  o.x = (short)f2bf(f.x); o.y = (short)f2bf(f.y);
  o.z = (short)f2bf(f.z); o.w = (short)f2bf(f.w);
  *(short4*)(out + 4 * (size_t)i) = o;
}

// ---------------- m97-style GEMM: C = A(MxK) * B(NxK)^T, z-batched ---------
// MODE 0: fp32 output, row-major ldc
// MODE 1: bf16 output, row-major ldc
// MODE 3: merged QKV epilogue. Cv = q base; k at +8M elems; vt at +16M elems.
//         col region 0 -> q row-major[row*1024+c], 1 -> k row-major,
//         2 -> vt[b*4194304 + c*4096 + s] (b=row>>12, s=row&4095), packed x4.
template <int MODE>
__global__ __launch_bounds__(256) void gemm_bt(const short* __restrict__ A,
                                               const short* __restrict__ B,
                                               void* __restrict__ Cv,
                                               int K, int ldc, float scale,
                                               long long aStr, long long bStr,
                                               long long cStr) {
  __shared__ short lA[128 * 64];
  __shared__ short lB[128 * 64];
  const int tid = threadIdx.x;
  const int w   = tid >> 6;     // wave 0..3
  const int l   = tid & 63;     // lane
  const int wm  = w >> 1, wn = w & 1;
  const long long tm = (long long)blockIdx.y * 128;
  const long long tn = (long long)blockIdx.x * 128;
  const long long z  = blockIdx.z;
  A += z * aStr;
  B += z * bStr;

  f32x4 acc[4][4] = {};

  const int lr  = l >> 3;        // row-in-segment (8 rows / 1KB wave load)
  const int lc  = (l & 7) * 8;   // col offset (elements)
  const int klo = (l >> 4) * 8;  // k offset within 32-chunk for A/B frags
  const int fr  = l & 15;        // m (or n) within 16-tile

  for (int k0 = 0; k0 < K; k0 += 64) {
#pragma unroll
    for (int t = 0; t < 4; ++t) {
      const int seg = w * 4 + t;
      gld_lds16(A + (tm + seg * 8 + lr) * (long long)K + k0 + lc, &lA[seg * 512]);
      gld_lds16(B + (tn + seg * 8 + lr) * (long long)K + k0 + lc, &lB[seg * 512]);
    }
    __syncthreads();
#pragma unroll
    for (int kk = 0; kk < 64; kk += 32) {
      short8 af[4], bfr[4];
#pragma unroll
      for (int i = 0; i < 4; ++i)
        af[i] = *(const short8*)&lA[(wm * 64 + i * 16 + fr) * 64 + kk + klo];
#pragma unroll
      for (int j = 0; j < 4; ++j)
        bfr[j] = *(const short8*)&lB[(wn * 64 + j * 16 + fr) * 64 + kk + klo];
#pragma unroll
      for (int i = 0; i < 4; ++i)
#pragma unroll
        for (int j = 0; j < 4; ++j)
          acc[i][j] = __builtin_amdgcn_mfma_f32_16x16x32_bf16(af[i], bfr[j], acc[i][j], 0, 0, 0);
    }
    __syncthreads();
  }

  // epilogue: within a 16x16 tile, row=(l>>4)*4+r, col=l&15
  const int rb = (l >> 4) * 4;
  if (MODE == 0) {
    float* dst = (float*)Cv + z * cStr;
#pragma unroll
    for (int i = 0; i < 4; ++i)
#pragma unroll
      for (int j = 0; j < 4; ++j)
#pragma unroll
        for (int r = 0; r < 4; ++r) {
          const long long row = tm + wm * 64 + i * 16 + rb + r;
          const long long col = tn + wn * 64 + j * 16 + fr;
          dst[row * ldc + col] = acc[i][j][r] * scale;
        }
  } else if (MODE == 1) {
    unsigned short* dst = (unsigned short*)Cv + z * cStr;
#pragma unroll
    for (int i = 0; i < 4; ++i)
#pragma unroll
      for (int j = 0; j < 4; ++j)
#pragma unroll
        for (int r = 0; r < 4; ++r) {
          const long long row = tm + wm * 64 + i * 16 + rb + r;
          const long long col = tn + wn * 64 + j * 16 + fr;
          dst[row * ldc + col] = f2bf(acc[i][j][r] * scale);
        }
  } else {  // MODE 3
    const int region = (int)(tn >> 10);
    const int cbase  = (int)(tn & 1023) + wn * 64;
    if (region < 2) {
      unsigned short* dst = (unsigned short*)Cv + (long long)region * 8388608ll;
#pragma unroll
      for (int i = 0; i < 4; ++i)
#pragma unroll
        for (int j = 0; j < 4; ++j)
#pragma unroll
          for (int r = 0; r < 4; ++r) {
            const long long row = tm + wm * 64 + i * 16 + rb + r;
            const int col = cbase + j * 16 + fr;
            dst[row * 1024 + col] = f2bf(acc[i][j][r] * scale);
          }
    } else {
      unsigned short* dst = (unsigned short*)Cv + 16777216ll;
#pragma unroll
      for (int i = 0; i < 4; ++i)
#pragma unroll
        for (int j = 0; j < 4; ++j) {
          const long long row0 = tm + wm * 64 + i * 16 + rb;
          const long long b = row0 >> 12, s0 = row0 & 4095;
          const int c = cbase + j * 16 + fr;
          short4 pk;
          pk.x = (short)f2bf(acc[i][j][0] * scale);
          pk.y = (short)f2bf(acc[i][j][1] * scale);
          pk.z = (short)f2bf(acc[i][j][2] * scale);
          pk.w = (short)f2bf(acc[i][j][3] * scale);
          *(short4*)(dst + b * 4194304ll + (long long)c * 4096 + s0) = pk;
        }
    }
  }
}

// ---------------- row softmax over 4096 cols, bf16 in/out, fp32 math --------
__global__ __launch_bounds__(256) void softmax4096(const unsigned short* __restrict__ S,
                                                   unsigned short* __restrict__ P,
                                                   float scale) {
  __shared__ float redm[4], reds[4];
  const long long row = blockIdx.x;
  const int tid = threadIdx.x;
  const int w = tid >> 6, l = tid & 63;
  const unsigned short* src = S + row * 4096 + tid * 16;
  short8 r0 = *(const short8*)src;
  short8 r1 = *(const short8*)(src + 8);
  float v[16];
#pragma unroll
  for (int i = 0; i < 8; ++i) v[i] = bf2f((unsigned short)r0[i]) * scale;
#pragma unroll
  for (int i = 0; i < 8; ++i) v[8 + i] = bf2f((unsigned short)r1[i]) * scale;
  float m = v[0];
#pragma unroll
  for (int i = 1; i < 16; ++i) m = fmaxf(m, v[i]);
#pragma unroll
  for (int off = 32; off; off >>= 1) m = fmaxf(m, __shfl_xor(m, off));
  if (l == 0) redm[w] = m;
  __syncthreads();
  m = fmaxf(fmaxf(redm[0], redm[1]), fmaxf(redm[2], redm[3]));
  float sum = 0.f;
#pragma unroll
  for (int i = 0; i < 16; ++i) { v[i] = __expf(v[i] - m); sum += v[i]; }
#pragma unroll
  for (int off = 32; off; off >>= 1) sum += __shfl_xor(sum, off);
  if (l == 0) reds[w] = sum;
  __syncthreads();
  const float inv = 1.0f / (reds[0] + reds[1] + reds[2] + reds[3]);
  short8 o0, o1;
#pragma unroll
  for (int i = 0; i < 8; ++i) o0[i] = (short)f2bf(v[i] * inv);
#pragma unroll
  for (int i = 0; i < 8; ++i) o1[i] = (short)f2bf(v[8 + i] * inv);
  unsigned short* dst = P + row * 4096 + tid * 16;
  *(short8*)dst = o0;
  *(short8*)(dst + 8) = o1;
}

// ---------------- launch ----------------
extern "C" void kernel_launch(void* const* d_in, const int* in_sizes, int n_in,
                              void* d_out, int out_size, void* d_ws, size_t ws_size,
                              hipStream_t stream) {
  const float* x  = (const float*)d_in[0];
  const float* Wq = (const float*)d_in[1];
  const float* Wk = (const float*)d_in[2];
  const float* Wv = (const float*)d_in[3];
  const float* Wo = (const float*)d_in[4];
  float* out = (float*)d_out;

  // ws layout (bytes):
  // [0,16M)    xb    8192x1024 bf16
  // [16M,22M)  wqkv  3072x1024 bf16   [22M,24M) wo 1024x1024 bf16
  // [24M,40M)  q     [40M,56M) k      [56M,72M) vt[2][1024][4096]
  // [72M,88M)  ao    [88M,152M) scores 2 x 4096x4096 bf16 (batched path)
  char* ws = (char*)d_ws;
  short* xb   = (short*)ws;
  short* wqkv = (short*)(ws + (16ll << 20));
  short* wo   = wqkv + 3145728;
  short* q    = (short*)(ws + (24ll << 20));
  short* k    = q + 8388608;
  short* vt   = q + 16777216;
  short* ao   = (short*)(ws + (72ll << 20));
  short* sc   = (short*)(ws + (88ll << 20));

  const bool batched = ws_size >= 159383552ull;  // need 152 MiB
  dim3 blk(256);

  // casts (Wq/Wk/Wv into concatenated wqkv)
  cast_f32_to_bf16<<<8192, blk, 0, stream>>>((const float4*)x, xb, 2097152);
  cast_f32_to_bf16<<<1024, blk, 0, stream>>>((const float4*)Wq, wqkv, 262144);
  cast_f32_to_bf16<<<1024, blk, 0, stream>>>((const float4*)Wk, wqkv + 1048576, 262144);
  cast_f32_to_bf16<<<1024, blk, 0, stream>>>((const float4*)Wv, wqkv + 2097152, 262144);
  cast_f32_to_bf16<<<1024, blk, 0, stream>>>((const float4*)Wo, wo, 262144);

  // merged QKV projection: M=8192, N=3072, K=1024
  dim3 gqkv(24, 64, 1);
  gemm_bt<3><<<gqkv, blk, 0, stream>>>(xb, wqkv, q, 1024, 1024, 1.f, 0, 0, 0);

  if (batched) {
    // QK^T both batches, scale folded: M=N=4096, K=1024
    dim3 gs(32, 32, 2);
    gemm_bt<1><<<gs, blk, 0, stream>>>(q, k, sc, 1024, 4096, 0.03125f,
                                       4194304ll, 4194304ll, 16777216ll);
    softmax4096<<<8192, blk, 0, stream>>>((unsigned short*)sc, (unsigned short*)sc, 1.0f);
    // PV both batches: M=4096, N=1024, K=4096
    dim3 gpv(8, 32, 2);
    gemm_bt<1><<<gpv, blk, 0, stream>>>(sc, vt, ao, 4096, 1024, 1.f,
                                        16777216ll, 4194304ll, 4194304ll);
  } else {
    for (int b = 0; b < 2; ++b) {
      short* qb  = q  + (long long)b * 4194304;
      short* kb  = k  + (long long)b * 4194304;
      short* vb  = vt + (long long)b * 4194304;
      short* aob = ao + (long long)b * 4194304;
      dim3 gs(32, 32, 1);
      gemm_bt<1><<<gs, blk, 0, stream>>>(qb, kb, sc, 1024, 4096, 0.03125f, 0, 0, 0);
      softmax4096<<<4096, blk, 0, stream>>>((unsigned short*)sc, (unsigned short*)sc, 1.0f);
      dim3 gpv(8, 32, 1);
      gemm_bt<1><<<gpv, blk, 0, stream>>>(sc, vb, aob, 4096, 1024, 1.f, 0, 0, 0);
    }
  }

  // output projection: M=8192, N=1024, K=1024, fp32 out
  dim3 go(8, 64, 1);
  gemm_bt<0><<<go, blk, 0, stream>>>(ao, wo, out, 1024, 1024, 1.f, 0, 0, 0);
}

// Round 3
// 420.274 us; speedup vs baseline: 1.2385x; 1.0153x over previous
//
#include <hip/hip_runtime.h>
#include <hip/hip_bf16.h>

// ---------------- helpers ----------------
using short8 = __attribute__((ext_vector_type(8))) short;
using f32x4  = __attribute__((ext_vector_type(4))) float;

__device__ __forceinline__ unsigned short f2bf(float f) {
  union { float f; unsigned int u; } x; x.f = f;
  unsigned int r = (x.u + 0x7fffu + ((x.u >> 16) & 1u)) >> 16;
  return (unsigned short)r;
}

__device__ __forceinline__ void gld_lds16(const short* gp, short* lp) {
  __builtin_amdgcn_global_load_lds((const __attribute__((address_space(1))) void*)gp,
                                   (__attribute__((address_space(3))) void*)lp, 16, 0, 0);
}

// ---------------- fp32 -> bf16 cast (vectorized) ----------------
__global__ __launch_bounds__(256) void cast_f32_to_bf16(const float4* __restrict__ in,
                                                        short* __restrict__ out, int n4) {
  int i = blockIdx.x * 256 + threadIdx.x;
  if (i >= n4) return;
  float4 f = in[i];
  short4 o;
  o.x = (short)f2bf(f.x); o.y = (short)f2bf(f.y);
  o.z = (short)f2bf(f.z); o.w = (short)f2bf(f.w);
  *(short4*)(out + 4 * (size_t)i) = o;
}

__global__ __launch_bounds__(256) void zero_f32(float* __restrict__ p, int n) {
  int i = blockIdx.x * 256 + threadIdx.x;
  if (i < n) p[i] = 0.f;
}

// ---------------- m97-style GEMM: C = A(MxK) * B(NxK)^T, z-batched ---------
// All modes except the QKV v-region use SWAPPED mfma operands so the acc tile
// is transposed: lane holds row = fr (seq), cols = rb..rb+3 -> packed stores.
// MODE 0: fp32 output, row-major ldc, float4 stores (output projection)
// MODE 2: merged QKV. region 0/1 (blockIdx.x<16): q/k row-major packed;
//         region 2: v transposed [b*4194304 + c*4096 + s] packed along s
//         (normal operand order for that region).
// MODE 4: QK^T + exp(scale*s) fused, bf16 packed stores, row-sum atomics.
// MODE 5: PV with 1/rowsum normalization in epilogue, bf16 packed stores.
template <int MODE>
__global__ __launch_bounds__(256) void gemm_bt(const short* __restrict__ A,
                                               const short* __restrict__ B,
                                               void* __restrict__ Cv,
                                               float* __restrict__ sums,
                                               int K, int ldc, float scale,
                                               long long aStr, long long bStr,
                                               long long cStr) {
  __shared__ short lA[128 * 64];
  __shared__ short lB[128 * 64];
  const int tid = threadIdx.x;
  const int w   = tid >> 6;     // wave 0..3
  const int l   = tid & 63;     // lane
  const int wm  = w >> 1, wn = w & 1;
  const long long tm = (long long)blockIdx.y * 128;
  const long long tn = (long long)blockIdx.x * 128;
  const long long z  = blockIdx.z;
  A += z * aStr;
  B += z * bStr;

  const bool swp = (MODE == 2) ? (blockIdx.x < 16) : true;

  f32x4 acc[4][4] = {};

  const int lr  = l >> 3;        // row-in-segment (8 rows / 1KB wave load)
  const int lc  = (l & 7) * 8;   // col offset (elements)
  const int klo = (l >> 4) * 8;  // k offset within 32-chunk for A/B frags
  const int fr  = l & 15;        // m (or n) within 16-tile

  for (int k0 = 0; k0 < K; k0 += 64) {
#pragma unroll
    for (int t = 0; t < 4; ++t) {
      const int seg = w * 4 + t;
      gld_lds16(A + (tm + seg * 8 + lr) * (long long)K + k0 + lc, &lA[seg * 512]);
      gld_lds16(B + (tn + seg * 8 + lr) * (long long)K + k0 + lc, &lB[seg * 512]);
    }
    __syncthreads();
#pragma unroll
    for (int kk = 0; kk < 64; kk += 32) {
      short8 af[4], bfr[4];
#pragma unroll
      for (int i = 0; i < 4; ++i)
        af[i] = *(const short8*)&lA[(wm * 64 + i * 16 + fr) * 64 + kk + klo];
#pragma unroll
      for (int j = 0; j < 4; ++j)
        bfr[j] = *(const short8*)&lB[(wn * 64 + j * 16 + fr) * 64 + kk + klo];
      if (swp) {
#pragma unroll
        for (int i = 0; i < 4; ++i)
#pragma unroll
          for (int j = 0; j < 4; ++j)
            acc[i][j] = __builtin_amdgcn_mfma_f32_16x16x32_bf16(bfr[j], af[i], acc[i][j], 0, 0, 0);
      } else {
#pragma unroll
        for (int i = 0; i < 4; ++i)
#pragma unroll
          for (int j = 0; j < 4; ++j)
            acc[i][j] = __builtin_amdgcn_mfma_f32_16x16x32_bf16(af[i], bfr[j], acc[i][j], 0, 0, 0);
      }
    }
    __syncthreads();
  }

  const int rb = (l >> 4) * 4;   // col base within 16-tile (swapped layout)

  if (MODE == 0) {
    float* dst = (float*)Cv + z * cStr;
#pragma unroll
    for (int i = 0; i < 4; ++i) {
      const long long row = tm + wm * 64 + i * 16 + fr;
#pragma unroll
      for (int j = 0; j < 4; ++j) {
        const long long colb = tn + wn * 64 + j * 16 + rb;
        *(f32x4*)((float*)dst + row * ldc + colb) = acc[i][j];
      }
    }
  } else if (MODE == 2) {
    const int cb0 = (int)(tn & 1023) + wn * 64;
    if (swp) {
      const int region = (int)(tn >> 10);
      unsigned short* dst = (unsigned short*)Cv + (long long)region * 8388608ll;
#pragma unroll
      for (int i = 0; i < 4; ++i) {
        const long long row = tm + wm * 64 + i * 16 + fr;
#pragma unroll
        for (int j = 0; j < 4; ++j) {
          const int colb = cb0 + j * 16 + rb;
          short4 pk;
          pk.x = (short)f2bf(acc[i][j][0]); pk.y = (short)f2bf(acc[i][j][1]);
          pk.z = (short)f2bf(acc[i][j][2]); pk.w = (short)f2bf(acc[i][j][3]);
          *(short4*)(dst + row * 1024 + colb) = pk;
        }
      }
    } else {  // v region: normal layout, pack along sequence dim
      unsigned short* dst = (unsigned short*)Cv + 16777216ll;
#pragma unroll
      for (int i = 0; i < 4; ++i)
#pragma unroll
        for (int j = 0; j < 4; ++j) {
          const long long row0 = tm + wm * 64 + i * 16 + rb;
          const long long b = row0 >> 12, s0 = row0 & 4095;
          const int c = cb0 + j * 16 + fr;
          short4 pk;
          pk.x = (short)f2bf(acc[i][j][0]); pk.y = (short)f2bf(acc[i][j][1]);
          pk.z = (short)f2bf(acc[i][j][2]); pk.w = (short)f2bf(acc[i][j][3]);
          *(short4*)(dst + b * 4194304ll + (long long)c * 4096 + s0) = pk;
        }
    }
  } else if (MODE == 4) {
    unsigned short* dst = (unsigned short*)Cv + z * cStr;
    float* sm = sums + z * 4096;
#pragma unroll
    for (int i = 0; i < 4; ++i) {
      const long long row = tm + wm * 64 + i * 16 + fr;
      float rs = 0.f;
#pragma unroll
      for (int j = 0; j < 4; ++j) {
        const long long colb = tn + wn * 64 + j * 16 + rb;
        short4 pk;
        float e0 = __expf(acc[i][j][0] * scale);
        float e1 = __expf(acc[i][j][1] * scale);
        float e2 = __expf(acc[i][j][2] * scale);
        float e3 = __expf(acc[i][j][3] * scale);
        rs += (e0 + e1) + (e2 + e3);
        pk.x = (short)f2bf(e0); pk.y = (short)f2bf(e1);
        pk.z = (short)f2bf(e2); pk.w = (short)f2bf(e3);
        *(short4*)(dst + row * ldc + colb) = pk;
      }
      rs += __shfl_xor(rs, 16);
      rs += __shfl_xor(rs, 32);
      if (l < 16) atomicAdd(sm + tm + wm * 64 + i * 16 + l, rs);
    }
  } else {  // MODE 5
    unsigned short* dst = (unsigned short*)Cv + z * cStr;
    const float* sm = sums + z * 4096;
#pragma unroll
    for (int i = 0; i < 4; ++i) {
      const long long row = tm + wm * 64 + i * 16 + fr;
      const float inv = 1.0f / sm[row];
#pragma unroll
      for (int j = 0; j < 4; ++j) {
        const long long colb = tn + wn * 64 + j * 16 + rb;
        short4 pk;
        pk.x = (short)f2bf(acc[i][j][0] * inv); pk.y = (short)f2bf(acc[i][j][1] * inv);
        pk.z = (short)f2bf(acc[i][j][2] * inv); pk.w = (short)f2bf(acc[i][j][3] * inv);
        *(short4*)(dst + row * ldc + colb) = pk;
      }
    }
  }
}

// ---------------- launch ----------------
extern "C" void kernel_launch(void* const* d_in, const int* in_sizes, int n_in,
                              void* d_out, int out_size, void* d_ws, size_t ws_size,
                              hipStream_t stream) {
  const float* x  = (const float*)d_in[0];
  const float* Wq = (const float*)d_in[1];
  const float* Wk = (const float*)d_in[2];
  const float* Wv = (const float*)d_in[3];
  const float* Wo = (const float*)d_in[4];
  float* out = (float*)d_out;

  // ws layout (bytes):
  // [0,16M)    xb    8192x1024 bf16  (first 32KB reused as row-sums after QKV proj)
  // [16M,22M)  wqkv  3072x1024 bf16   [22M,24M) wo 1024x1024 bf16
  // [24M,40M)  q     [40M,56M) k      [56M,72M) vt[2][1024][4096]
  // [72M,88M)  ao    [88M,152M) scores 2 x 4096x4096 bf16 (batched path)
  char* ws = (char*)d_ws;
  short* xb   = (short*)ws;
  short* wqkv = (short*)(ws + (16ll << 20));
  short* wo   = wqkv + 3145728;
  short* q    = (short*)(ws + (24ll << 20));
  short* k    = q + 8388608;
  short* vt   = q + 16777216;
  short* ao   = (short*)(ws + (72ll << 20));
  short* sc   = (short*)(ws + (88ll << 20));
  float* sums = (float*)ws;   // 8192 floats; xb is dead after QKV projection

  const bool batched = ws_size >= 159383552ull;  // need 152 MiB
  dim3 blk(256);

  // casts (Wq/Wk/Wv into concatenated wqkv)
  cast_f32_to_bf16<<<8192, blk, 0, stream>>>((const float4*)x, xb, 2097152);
  cast_f32_to_bf16<<<1024, blk, 0, stream>>>((const float4*)Wq, wqkv, 262144);
  cast_f32_to_bf16<<<1024, blk, 0, stream>>>((const float4*)Wk, wqkv + 1048576, 262144);
  cast_f32_to_bf16<<<1024, blk, 0, stream>>>((const float4*)Wv, wqkv + 2097152, 262144);
  cast_f32_to_bf16<<<1024, blk, 0, stream>>>((const float4*)Wo, wo, 262144);

  // merged QKV projection: M=8192, N=3072, K=1024
  dim3 gqkv(24, 64, 1);
  gemm_bt<2><<<gqkv, blk, 0, stream>>>(xb, wqkv, q, nullptr, 1024, 1024, 1.f, 0, 0, 0);

  if (batched) {
    zero_f32<<<32, blk, 0, stream>>>(sums, 8192);
    // QK^T + exp, both batches: M=N=4096, K=1024
    dim3 gs(32, 32, 2);
    gemm_bt<4><<<gs, blk, 0, stream>>>(q, k, sc, sums, 1024, 4096, 0.03125f,
                                       4194304ll, 4194304ll, 16777216ll);
    // PV + normalize, both batches: M=4096, N=1024, K=4096
    dim3 gpv(8, 32, 2);
    gemm_bt<5><<<gpv, blk, 0, stream>>>(sc, vt, ao, sums, 4096, 1024, 1.f,
                                        16777216ll, 4194304ll, 4194304ll);
  } else {
    for (int b = 0; b < 2; ++b) {
      short* qb  = q  + (long long)b * 4194304;
      short* kb  = k  + (long long)b * 4194304;
      short* vb  = vt + (long long)b * 4194304;
      short* aob = ao + (long long)b * 4194304;
      zero_f32<<<16, blk, 0, stream>>>(sums, 4096);
      dim3 gs(32, 32, 1);
      gemm_bt<4><<<gs, blk, 0, stream>>>(qb, kb, sc, sums, 1024, 4096, 0.03125f, 0, 0, 0);
      dim3 gpv(8, 32, 1);
      gemm_bt<5><<<gpv, blk, 0, stream>>>(sc, vb, aob, sums, 4096, 1024, 1.f, 0, 0, 0);
    }
  }

  // output projection: M=8192, N=1024, K=1024, fp32 out
  dim3 go(8, 64, 1);
  gemm_bt<0><<<go, blk, 0, stream>>>(ao, wo, out, nullptr, 1024, 1024, 1.f, 0, 0, 0);
}

// Round 4
// 384.628 us; speedup vs baseline: 1.3533x; 1.0927x over previous
//
#include <hip/hip_runtime.h>
#include <hip/hip_bf16.h>

// ---------------- helpers ----------------
using short8 = __attribute__((ext_vector_type(8))) short;
using f32x4  = __attribute__((ext_vector_type(4))) float;

__device__ __forceinline__ unsigned short f2bf(float f) {
  union { float f; unsigned int u; } x; x.f = f;
  unsigned int r = (x.u + 0x7fffu + ((x.u >> 16) & 1u)) >> 16;
  return (unsigned short)r;
}

__device__ __forceinline__ void gld_lds16(const short* gp, short* lp) {
  __builtin_amdgcn_global_load_lds((const __attribute__((address_space(1))) void*)gp,
                                   (__attribute__((address_space(3))) void*)lp, 16, 0, 0);
}

// ---------------- fp32 -> bf16 cast (vectorized) ----------------
__global__ __launch_bounds__(256) void cast_f32_to_bf16(const float4* __restrict__ in,
                                                        short* __restrict__ out, int n4) {
  int i = blockIdx.x * 256 + threadIdx.x;
  if (i >= n4) return;
  float4 f = in[i];
  short4 o;
  o.x = (short)f2bf(f.x); o.y = (short)f2bf(f.y);
  o.z = (short)f2bf(f.z); o.w = (short)f2bf(f.w);
  *(short4*)(out + 4 * (size_t)i) = o;
}

__global__ __launch_bounds__(256) void zero_f32(float* __restrict__ p, int n) {
  int i = blockIdx.x * 256 + threadIdx.x;
  if (i < n) p[i] = 0.f;
}

// ---------------- m97-style GEMM: C = A(MxK) * B(NxK)^T, z-batched ---------
// LDS tiles are XOR-swizzled: row r's 16B chunk c lives at slot (c ^ (r&7)).
// Staging permutes which chunk each lane fetches (slot = lane*16B is fixed by
// global_load_lds); reads address chunk (G ^ (R&7)). Kills the 16-way bank
// collision of the unswizzled 128B-row layout.
// All modes except the QKV v-region use SWAPPED mfma operands so the acc tile
// is transposed: lane holds row = fr (seq), cols = rb..rb+3 -> packed stores.
// MODE 0: fp32 output, row-major ldc, float4 stores (output projection)
// MODE 2: merged QKV. region 0/1 (blockIdx.x<16): q/k row-major packed;
//         region 2: v transposed [b*4194304 + c*4096 + s] packed along s.
// MODE 4: QK^T + exp(scale*s) fused, bf16 packed stores, row-sum atomics.
// MODE 5: PV with 1/rowsum normalization in epilogue, bf16 packed stores.
template <int MODE>
__global__ __launch_bounds__(256) void gemm_bt(const short* __restrict__ A,
                                               const short* __restrict__ B,
                                               void* __restrict__ Cv,
                                               float* __restrict__ sums,
                                               int K, int ldc, float scale,
                                               long long aStr, long long bStr,
                                               long long cStr) {
  __shared__ short lA[128 * 64];
  __shared__ short lB[128 * 64];
  const int tid = threadIdx.x;
  const int w   = tid >> 6;     // wave 0..3
  const int l   = tid & 63;     // lane
  const int wm  = w >> 1, wn = w & 1;
  const long long tm = (long long)blockIdx.y * 128;
  const long long tn = (long long)blockIdx.x * 128;
  const long long z  = blockIdx.z;
  A += z * aStr;
  B += z * bStr;

  const bool swp = (MODE == 2) ? (blockIdx.x < 16) : true;

  f32x4 acc[4][4] = {};

  const int lr   = l >> 3;                         // row-in-segment
  const int scw  = ((l & 7) ^ (lr & 7)) * 8;       // swizzled fetch chunk (shorts)
  const int q4   = l >> 4;                         // quad
  const int fr   = l & 15;                         // m (or n) within 16-tile
  const int xr   = fr & 7;                         // row-phase for read swizzle

  for (int k0 = 0; k0 < K; k0 += 64) {
#pragma unroll
    for (int t = 0; t < 4; ++t) {
      const int seg = w * 4 + t;
      gld_lds16(A + (tm + seg * 8 + lr) * (long long)K + k0 + scw, &lA[seg * 512]);
      gld_lds16(B + (tn + seg * 8 + lr) * (long long)K + k0 + scw, &lB[seg * 512]);
    }
    __syncthreads();
#pragma unroll
    for (int kk = 0; kk < 64; kk += 32) {
      const int cs = ((((kk >> 3)) + q4) ^ xr) << 3;   // swizzled chunk offset (shorts)
      short8 af[4], bfr[4];
#pragma unroll
      for (int i = 0; i < 4; ++i)
        af[i] = *(const short8*)&lA[(wm * 64 + i * 16 + fr) * 64 + cs];
#pragma unroll
      for (int j = 0; j < 4; ++j)
        bfr[j] = *(const short8*)&lB[(wn * 64 + j * 16 + fr) * 64 + cs];
      if (swp) {
#pragma unroll
        for (int i = 0; i < 4; ++i)
#pragma unroll
          for (int j = 0; j < 4; ++j)
            acc[i][j] = __builtin_amdgcn_mfma_f32_16x16x32_bf16(bfr[j], af[i], acc[i][j], 0, 0, 0);
      } else {
#pragma unroll
        for (int i = 0; i < 4; ++i)
#pragma unroll
          for (int j = 0; j < 4; ++j)
            acc[i][j] = __builtin_amdgcn_mfma_f32_16x16x32_bf16(af[i], bfr[j], acc[i][j], 0, 0, 0);
      }
    }
    __syncthreads();
  }

  const int rb = (l >> 4) * 4;   // col base within 16-tile (swapped layout)

  if (MODE == 0) {
    float* dst = (float*)Cv + z * cStr;
#pragma unroll
    for (int i = 0; i < 4; ++i) {
      const long long row = tm + wm * 64 + i * 16 + fr;
#pragma unroll
      for (int j = 0; j < 4; ++j) {
        const long long colb = tn + wn * 64 + j * 16 + rb;
        *(f32x4*)((float*)dst + row * ldc + colb) = acc[i][j];
      }
    }
  } else if (MODE == 2) {
    const int cb0 = (int)(tn & 1023) + wn * 64;
    if (swp) {
      const int region = (int)(tn >> 10);
      unsigned short* dst = (unsigned short*)Cv + (long long)region * 8388608ll;
#pragma unroll
      for (int i = 0; i < 4; ++i) {
        const long long row = tm + wm * 64 + i * 16 + fr;
#pragma unroll
        for (int j = 0; j < 4; ++j) {
          const int colb = cb0 + j * 16 + rb;
          short4 pk;
          pk.x = (short)f2bf(acc[i][j][0]); pk.y = (short)f2bf(acc[i][j][1]);
          pk.z = (short)f2bf(acc[i][j][2]); pk.w = (short)f2bf(acc[i][j][3]);
          *(short4*)(dst + row * 1024 + colb) = pk;
        }
      }
    } else {  // v region: normal layout, pack along sequence dim
      unsigned short* dst = (unsigned short*)Cv + 16777216ll;
#pragma unroll
      for (int i = 0; i < 4; ++i)
#pragma unroll
        for (int j = 0; j < 4; ++j) {
          const long long row0 = tm + wm * 64 + i * 16 + rb;
          const long long b = row0 >> 12, s0 = row0 & 4095;
          const int c = cb0 + j * 16 + fr;
          short4 pk;
          pk.x = (short)f2bf(acc[i][j][0]); pk.y = (short)f2bf(acc[i][j][1]);
          pk.z = (short)f2bf(acc[i][j][2]); pk.w = (short)f2bf(acc[i][j][3]);
          *(short4*)(dst + b * 4194304ll + (long long)c * 4096 + s0) = pk;
        }
    }
  } else if (MODE == 4) {
    unsigned short* dst = (unsigned short*)Cv + z * cStr;
    float* sm = sums + z * 4096;
#pragma unroll
    for (int i = 0; i < 4; ++i) {
      const long long row = tm + wm * 64 + i * 16 + fr;
      float rs = 0.f;
#pragma unroll
      for (int j = 0; j < 4; ++j) {
        const long long colb = tn + wn * 64 + j * 16 + rb;
        short4 pk;
        float e0 = __expf(acc[i][j][0] * scale);
        float e1 = __expf(acc[i][j][1] * scale);
        float e2 = __expf(acc[i][j][2] * scale);
        float e3 = __expf(acc[i][j][3] * scale);
        rs += (e0 + e1) + (e2 + e3);
        pk.x = (short)f2bf(e0); pk.y = (short)f2bf(e1);
        pk.z = (short)f2bf(e2); pk.w = (short)f2bf(e3);
        *(short4*)(dst + row * ldc + colb) = pk;
      }
      rs += __shfl_xor(rs, 16);
      rs += __shfl_xor(rs, 32);
      if (l < 16) atomicAdd(sm + tm + wm * 64 + i * 16 + l, rs);
    }
  } else {  // MODE 5
    unsigned short* dst = (unsigned short*)Cv + z * cStr;
    const float* sm = sums + z * 4096;
#pragma unroll
    for (int i = 0; i < 4; ++i) {
      const long long row = tm + wm * 64 + i * 16 + fr;
      const float inv = 1.0f / sm[row];
#pragma unroll
      for (int j = 0; j < 4; ++j) {
        const long long colb = tn + wn * 64 + j * 16 + rb;
        short4 pk;
        pk.x = (short)f2bf(acc[i][j][0] * inv); pk.y = (short)f2bf(acc[i][j][1] * inv);
        pk.z = (short)f2bf(acc[i][j][2] * inv); pk.w = (short)f2bf(acc[i][j][3] * inv);
        *(short4*)(dst + row * ldc + colb) = pk;
      }
    }
  }
}

// ---------------- launch ----------------
extern "C" void kernel_launch(void* const* d_in, const int* in_sizes, int n_in,
                              void* d_out, int out_size, void* d_ws, size_t ws_size,
                              hipStream_t stream) {
  const float* x  = (const float*)d_in[0];
  const float* Wq = (const float*)d_in[1];
  const float* Wk = (const float*)d_in[2];
  const float* Wv = (const float*)d_in[3];
  const float* Wo = (const float*)d_in[4];
  float* out = (float*)d_out;

  // ws layout (bytes):
  // [0,16M)    xb    8192x1024 bf16  (first 32KB reused as row-sums after QKV proj)
  // [16M,22M)  wqkv  3072x1024 bf16   [22M,24M) wo 1024x1024 bf16
  // [24M,40M)  q     [40M,56M) k      [56M,72M) vt[2][1024][4096]
  // [72M,88M)  ao    [88M,152M) scores 2 x 4096x4096 bf16 (batched path)
  char* ws = (char*)d_ws;
  short* xb   = (short*)ws;
  short* wqkv = (short*)(ws + (16ll << 20));
  short* wo   = wqkv + 3145728;
  short* q    = (short*)(ws + (24ll << 20));
  short* k    = q + 8388608;
  short* vt   = q + 16777216;
  short* ao   = (short*)(ws + (72ll << 20));
  short* sc   = (short*)(ws + (88ll << 20));
  float* sums = (float*)ws;   // 8192 floats; xb is dead after QKV projection

  const bool batched = ws_size >= 159383552ull;  // need 152 MiB
  dim3 blk(256);

  // casts (Wq/Wk/Wv into concatenated wqkv)
  cast_f32_to_bf16<<<8192, blk, 0, stream>>>((const float4*)x, xb, 2097152);
  cast_f32_to_bf16<<<1024, blk, 0, stream>>>((const float4*)Wq, wqkv, 262144);
  cast_f32_to_bf16<<<1024, blk, 0, stream>>>((const float4*)Wk, wqkv + 1048576, 262144);
  cast_f32_to_bf16<<<1024, blk, 0, stream>>>((const float4*)Wv, wqkv + 2097152, 262144);
  cast_f32_to_bf16<<<1024, blk, 0, stream>>>((const float4*)Wo, wo, 262144);

  // merged QKV projection: M=8192, N=3072, K=1024
  dim3 gqkv(24, 64, 1);
  gemm_bt<2><<<gqkv, blk, 0, stream>>>(xb, wqkv, q, nullptr, 1024, 1024, 1.f, 0, 0, 0);

  if (batched) {
    zero_f32<<<32, blk, 0, stream>>>(sums, 8192);
    // QK^T + exp, both batches: M=N=4096, K=1024
    dim3 gs(32, 32, 2);
    gemm_bt<4><<<gs, blk, 0, stream>>>(q, k, sc, sums, 1024, 4096, 0.03125f,
                                       4194304ll, 4194304ll, 16777216ll);
    // PV + normalize, both batches: M=4096, N=1024, K=4096
    dim3 gpv(8, 32, 2);
    gemm_bt<5><<<gpv, blk, 0, stream>>>(sc, vt, ao, sums, 4096, 1024, 1.f,
                                        16777216ll, 4194304ll, 4194304ll);
  } else {
    for (int b = 0; b < 2; ++b) {
      short* qb  = q  + (long long)b * 4194304;
      short* kb  = k  + (long long)b * 4194304;
      short* vb  = vt + (long long)b * 4194304;
      short* aob = ao + (long long)b * 4194304;
      zero_f32<<<16, blk, 0, stream>>>(sums, 4096);
      dim3 gs(32, 32, 1);
      gemm_bt<4><<<gs, blk, 0, stream>>>(qb, kb, sc, sums, 1024, 4096, 0.03125f, 0, 0, 0);
      dim3 gpv(8, 32, 1);
      gemm_bt<5><<<gpv, blk, 0, stream>>>(sc, vb, aob, sums, 4096, 1024, 1.f, 0, 0, 0);
    }
  }

  // output projection: M=8192, N=1024, K=1024, fp32 out
  dim3 go(8, 64, 1);
  gemm_bt<0><<<go, blk, 0, stream>>>(ao, wo, out, nullptr, 1024, 1024, 1.f, 0, 0, 0);
}

// Round 6
// 349.841 us; speedup vs baseline: 1.4879x; 1.0994x over previous
//
#include <hip/hip_runtime.h>
#include <hip/hip_bf16.h>

// ---------------- helpers ----------------
using short8 = __attribute__((ext_vector_type(8))) short;
using f32x4  = __attribute__((ext_vector_type(4))) float;

__device__ __forceinline__ unsigned short f2bf(float f) {
  union { float f; unsigned int u; } x; x.f = f;
  unsigned int r = (x.u + 0x7fffu + ((x.u >> 16) & 1u)) >> 16;
  return (unsigned short)r;
}

__device__ __forceinline__ void gld_lds16(const short* gp, short* lp) {
  __builtin_amdgcn_global_load_lds((const __attribute__((address_space(1))) void*)gp,
                                   (__attribute__((address_space(3))) void*)lp, 16, 0, 0);
}

// ------- merged cast: x -> xb, Wq/Wk/Wv -> wqkv, Wo -> wo -------------------
// NOTE: row-sums must NOT live in d_out — mixing plain stores + atomics +
// harness poison in the validated buffer diverged on graph replays (round 5).
__global__ __launch_bounds__(256) void cast_all(const float4* __restrict__ x,
                                                const float4* __restrict__ Wq,
                                                const float4* __restrict__ Wk,
                                                const float4* __restrict__ Wv,
                                                const float4* __restrict__ Wo,
                                                short* __restrict__ xb,
                                                short* __restrict__ wqkv,
                                                short* __restrict__ wo) {
  const int i = blockIdx.x * 256 + threadIdx.x;
  const float4* src;
  short* dst;
  if (i < 2097152) {               // x: 8192x1024 fp32 = 2,097,152 float4
    src = x + i;
    dst = xb + 4ll * i;
  } else {
    const int j = i - 2097152;
    const int w = j >> 18;         // 262144 float4 per weight
    const int off = j & 262143;
    src = (w == 0 ? Wq : w == 1 ? Wk : w == 2 ? Wv : Wo) + off;
    dst = (w < 3 ? wqkv + (long long)w * 1048576 : wo) + 4ll * off;
  }
  float4 f = *src;
  short4 o;
  o.x = (short)f2bf(f.x); o.y = (short)f2bf(f.y);
  o.z = (short)f2bf(f.z); o.w = (short)f2bf(f.w);
  *(short4*)dst = o;
}

__global__ __launch_bounds__(256) void zero_f32(float* __restrict__ p, int n) {
  int i = blockIdx.x * 256 + threadIdx.x;
  if (i < n) p[i] = 0.f;
}

// ---------------- m97-style GEMM: C = A(MxK) * B(NxK)^T, XCD-swizzled ------
// 1-D grid, id = x*ng + g, g=(y,z): the up-to-8 (x) blocks sharing an A-row-
// tile have ids congruent mod 8 -> same XCD -> A-tile reuse from that XCD's
// L2; B-tiles walk in lockstep across XCDs -> L3 temporal dedup.
// LDS tiles XOR-swizzled (chunk c of row r at slot c^(r&7)): 0 bank conflicts.
// All modes except the QKV v-region use SWAPPED mfma operands so the acc tile
// is transposed: lane holds row = fr, cols = rb..rb+3 -> packed stores.
// MODE 0: fp32 output, row-major ldc, float4 stores (output projection)
// MODE 2: merged QKV. x<16: q/k row-major packed; x>=16: v transposed
//         [b*4194304 + c*4096 + s] packed along s.
// MODE 4: QK^T + exp(scale*s) fused, bf16 packed stores, row-sum atomics.
// MODE 5: PV with 1/rowsum normalization in epilogue, bf16 packed stores.
template <int MODE>
__global__ __launch_bounds__(256) void gemm_bt(const short* __restrict__ A,
                                               const short* __restrict__ B,
                                               void* __restrict__ Cv,
                                               float* __restrict__ sums,
                                               int K, int ldc, float scale,
                                               long long aStr, long long bStr,
                                               long long cStr, int gy, int ng) {
  __shared__ short lA[128 * 64];
  __shared__ short lB[128 * 64];
  const int bid = blockIdx.x;
  const int bx  = bid / ng;
  const int g   = bid % ng;
  const int by  = g % gy;
  const long long z = g / gy;
  const int tid = threadIdx.x;
  const int w   = tid >> 6;     // wave 0..3
  const int l   = tid & 63;     // lane
  const int wm  = w >> 1, wn = w & 1;
  const long long tm = (long long)by * 128;
  const long long tn = (long long)bx * 128;
  A += z * aStr;
  B += z * bStr;

  const bool swp = (MODE == 2) ? (bx < 16) : true;

  f32x4 acc[4][4] = {};

  const int lr   = l >> 3;                         // row-in-segment
  const int scw  = ((l & 7) ^ (lr & 7)) * 8;       // swizzled fetch chunk (shorts)
  const int q4   = l >> 4;                         // quad
  const int fr   = l & 15;                         // m (or n) within 16-tile
  const int xr   = fr & 7;                         // row-phase for read swizzle

  for (int k0 = 0; k0 < K; k0 += 64) {
#pragma unroll
    for (int t = 0; t < 4; ++t) {
      const int seg = w * 4 + t;
      gld_lds16(A + (tm + seg * 8 + lr) * (long long)K + k0 + scw, &lA[seg * 512]);
      gld_lds16(B + (tn + seg * 8 + lr) * (long long)K + k0 + scw, &lB[seg * 512]);
    }
    __syncthreads();
#pragma unroll
    for (int kk = 0; kk < 64; kk += 32) {
      const int cs = ((((kk >> 3)) + q4) ^ xr) << 3;   // swizzled chunk offset
      short8 af[4], bfr[4];
#pragma unroll
      for (int i = 0; i < 4; ++i)
        af[i] = *(const short8*)&lA[(wm * 64 + i * 16 + fr) * 64 + cs];
#pragma unroll
      for (int j = 0; j < 4; ++j)
        bfr[j] = *(const short8*)&lB[(wn * 64 + j * 16 + fr) * 64 + cs];
      if (swp) {
#pragma unroll
        for (int i = 0; i < 4; ++i)
#pragma unroll
          for (int j = 0; j < 4; ++j)
            acc[i][j] = __builtin_amdgcn_mfma_f32_16x16x32_bf16(bfr[j], af[i], acc[i][j], 0, 0, 0);
      } else {
#pragma unroll
        for (int i = 0; i < 4; ++i)
#pragma unroll
          for (int j = 0; j < 4; ++j)
            acc[i][j] = __builtin_amdgcn_mfma_f32_16x16x32_bf16(af[i], bfr[j], acc[i][j], 0, 0, 0);
      }
    }
    __syncthreads();
  }

  const int rb = (l >> 4) * 4;   // col base within 16-tile (swapped layout)

  if (MODE == 0) {
    float* dst = (float*)Cv + z * cStr;
#pragma unroll
    for (int i = 0; i < 4; ++i) {
      const long long row = tm + wm * 64 + i * 16 + fr;
#pragma unroll
      for (int j = 0; j < 4; ++j) {
        const long long colb = tn + wn * 64 + j * 16 + rb;
        *(f32x4*)((float*)dst + row * ldc + colb) = acc[i][j];
      }
    }
  } else if (MODE == 2) {
    const int cb0 = (int)(tn & 1023) + wn * 64;
    if (swp) {
      const int region = (int)(tn >> 10);
      unsigned short* dst = (unsigned short*)Cv + (long long)region * 8388608ll;
#pragma unroll
      for (int i = 0; i < 4; ++i) {
        const long long row = tm + wm * 64 + i * 16 + fr;
#pragma unroll
        for (int j = 0; j < 4; ++j) {
          const int colb = cb0 + j * 16 + rb;
          short4 pk;
          pk.x = (short)f2bf(acc[i][j][0]); pk.y = (short)f2bf(acc[i][j][1]);
          pk.z = (short)f2bf(acc[i][j][2]); pk.w = (short)f2bf(acc[i][j][3]);
          *(short4*)(dst + row * 1024 + colb) = pk;
        }
      }
    } else {  // v region: normal layout, pack along sequence dim
      unsigned short* dst = (unsigned short*)Cv + 16777216ll;
#pragma unroll
      for (int i = 0; i < 4; ++i)
#pragma unroll
        for (int j = 0; j < 4; ++j) {
          const long long row0 = tm + wm * 64 + i * 16 + rb;
          const long long b = row0 >> 12, s0 = row0 & 4095;
          const int c = cb0 + j * 16 + fr;
          short4 pk;
          pk.x = (short)f2bf(acc[i][j][0]); pk.y = (short)f2bf(acc[i][j][1]);
          pk.z = (short)f2bf(acc[i][j][2]); pk.w = (short)f2bf(acc[i][j][3]);
          *(short4*)(dst + b * 4194304ll + (long long)c * 4096 + s0) = pk;
        }
    }
  } else if (MODE == 4) {
    unsigned short* dst = (unsigned short*)Cv + z * cStr;
    float* sm = sums + z * 4096;
#pragma unroll
    for (int i = 0; i < 4; ++i) {
      const long long row = tm + wm * 64 + i * 16 + fr;
      float rs = 0.f;
#pragma unroll
      for (int j = 0; j < 4; ++j) {
        const long long colb = tn + wn * 64 + j * 16 + rb;
        short4 pk;
        float e0 = __expf(acc[i][j][0] * scale);
        float e1 = __expf(acc[i][j][1] * scale);
        float e2 = __expf(acc[i][j][2] * scale);
        float e3 = __expf(acc[i][j][3] * scale);
        rs += (e0 + e1) + (e2 + e3);
        pk.x = (short)f2bf(e0); pk.y = (short)f2bf(e1);
        pk.z = (short)f2bf(e2); pk.w = (short)f2bf(e3);
        *(short4*)(dst + row * ldc + colb) = pk;
      }
      rs += __shfl_xor(rs, 16);
      rs += __shfl_xor(rs, 32);
      if (l < 16) atomicAdd(sm + tm + wm * 64 + i * 16 + l, rs);
    }
  } else {  // MODE 5
    unsigned short* dst = (unsigned short*)Cv + z * cStr;
    const float* sm = sums + z * 4096;
#pragma unroll
    for (int i = 0; i < 4; ++i) {
      const long long row = tm + wm * 64 + i * 16 + fr;
      const float inv = 1.0f / sm[row];
#pragma unroll
      for (int j = 0; j < 4; ++j) {
        const long long colb = tn + wn * 64 + j * 16 + rb;
        short4 pk;
        pk.x = (short)f2bf(acc[i][j][0] * inv); pk.y = (short)f2bf(acc[i][j][1] * inv);
        pk.z = (short)f2bf(acc[i][j][2] * inv); pk.w = (short)f2bf(acc[i][j][3] * inv);
        *(short4*)(dst + row * ldc + colb) = pk;
      }
    }
  }
}

// ---------------- launch ----------------
extern "C" void kernel_launch(void* const* d_in, const int* in_sizes, int n_in,
                              void* d_out, int out_size, void* d_ws, size_t ws_size,
                              hipStream_t stream) {
  const float* x  = (const float*)d_in[0];
  const float* Wq = (const float*)d_in[1];
  const float* Wk = (const float*)d_in[2];
  const float* Wv = (const float*)d_in[3];
  const float* Wo = (const float*)d_in[4];
  float* out = (float*)d_out;

  // ws layout (bytes):
  // [0,16M)    xb    8192x1024 bf16  (head 32KB reused as row-sums AFTER QKV proj)
  // [16M,22M)  wqkv  3072x1024 bf16   [22M,24M) wo 1024x1024 bf16
  // [24M,40M)  q     [40M,56M) k      [56M,72M) vt[2][1024][4096]
  // [72M,88M)  ao    [88M,152M) scores 2 x 4096x4096 bf16 (batched path)
  char* ws = (char*)d_ws;
  short* xb   = (short*)ws;
  short* wqkv = (short*)(ws + (16ll << 20));
  short* wo   = wqkv + 3145728;
  short* q    = (short*)(ws + (24ll << 20));
  short* k    = q + 8388608;
  short* vt   = q + 16777216;
  short* ao   = (short*)(ws + (72ll << 20));
  short* sc   = (short*)(ws + (88ll << 20));
  float* sums = (float*)ws;   // xb head is dead after QKV projection

  const bool batched = ws_size >= 159383552ull;  // need 152 MiB
  dim3 blk(256);

  // merged casts: 3,145,728 float4 -> 12288 blocks exactly
  cast_all<<<12288, blk, 0, stream>>>((const float4*)x, (const float4*)Wq,
                                      (const float4*)Wk, (const float4*)Wv,
                                      (const float4*)Wo, xb, wqkv, wo);

  // merged QKV projection: M=8192, N=3072, K=1024; grid x=24, g=64
  gemm_bt<2><<<24 * 64, blk, 0, stream>>>(xb, wqkv, q, nullptr, 1024, 1024, 1.f,
                                          0, 0, 0, 64, 64);

  if (batched) {
    zero_f32<<<32, blk, 0, stream>>>(sums, 8192);   // xb head now dead
    // QK^T + exp, both batches: x=32, g=(y32,z2)=64
    gemm_bt<4><<<32 * 64, blk, 0, stream>>>(q, k, sc, sums, 1024, 4096, 0.03125f,
                                            4194304ll, 4194304ll, 16777216ll, 32, 64);
    // PV + normalize, both batches: x=8, g=64
    gemm_bt<5><<<8 * 64, blk, 0, stream>>>(sc, vt, ao, sums, 4096, 1024, 1.f,
                                           16777216ll, 4194304ll, 4194304ll, 32, 64);
  } else {
    for (int b = 0; b < 2; ++b) {
      short* qb  = q  + (long long)b * 4194304;
      short* kb  = k  + (long long)b * 4194304;
      short* vb  = vt + (long long)b * 4194304;
      short* aob = ao + (long long)b * 4194304;
      zero_f32<<<16, blk, 0, stream>>>(sums, 4096);
      gemm_bt<4><<<32 * 32, blk, 0, stream>>>(qb, kb, sc, sums, 1024, 4096, 0.03125f,
                                              0, 0, 0, 32, 32);
      gemm_bt<5><<<8 * 32, blk, 0, stream>>>(sc, vb, aob, sums, 4096, 1024, 1.f,
                                             0, 0, 0, 32, 32);
    }
  }

  // output projection: M=8192, N=1024, K=1024, fp32 out; x=8, g=64
  gemm_bt<0><<<8 * 64, blk, 0, stream>>>(ao, wo, out, nullptr, 1024, 1024, 1.f,
                                         0, 0, 0, 64, 64);
}

// Round 7
// 348.818 us; speedup vs baseline: 1.4922x; 1.0029x over previous
//
#include <hip/hip_runtime.h>
#include <hip/hip_bf16.h>

// ---------------- helpers ----------------
using short8 = __attribute__((ext_vector_type(8))) short;
using f32x4  = __attribute__((ext_vector_type(4))) float;

__device__ __forceinline__ unsigned short f2bf(float f) {
  union { float f; unsigned int u; } x; x.f = f;
  unsigned int r = (x.u + 0x7fffu + ((x.u >> 16) & 1u)) >> 16;
  return (unsigned short)r;
}

__device__ __forceinline__ void gld_lds16(const short* gp, short* lp) {
  __builtin_amdgcn_global_load_lds((const __attribute__((address_space(1))) void*)gp,
                                   (__attribute__((address_space(3))) void*)lp, 16, 0, 0);
}

// ------- merged cast kernel -------------------------------------------------
// blocks [0,8192):      x -> xb (bf16)
// blocks [8192,9216):   Wq -> wqkv slot0
// blocks [9216,10240):  Wk -> wqkv slot1
// blocks [10240,11264): Wo -> wo
// blocks [11264,11520): Wv -> wvT (64x64 LDS-tiled transpose, bf16)
// blocks [0,8):         also zero the 8192-float row-sum buffer (in ws).
__global__ __launch_bounds__(256) void cast_all(const float* __restrict__ x,
                                                const float* __restrict__ Wq,
                                                const float* __restrict__ Wk,
                                                const float* __restrict__ Wv,
                                                const float* __restrict__ Wo,
                                                short* __restrict__ xb,
                                                short* __restrict__ wqkv,
                                                short* __restrict__ wo,
                                                short* __restrict__ wvT,
                                                float4* __restrict__ sums4) {
  const int bid = blockIdx.x;
  const int tid = threadIdx.x;
  if (bid < 11264) {
    const float4* src;
    short* dst;
    const int i = bid * 256 + tid;
    if (bid < 8192) {
      src = (const float4*)x + i;
      dst = xb + 4ll * i;
    } else {
      const int j = i - 2097152;
      const int w = j >> 18;         // 262144 float4 per weight
      const int off = j & 262143;
      src = (const float4*)(w == 0 ? Wq : w == 1 ? Wk : Wo) + off;
      dst = (w == 0 ? wqkv : w == 1 ? wqkv + 1048576 : wo) + 4ll * off;
    }
    float4 f = *src;
    short4 o;
    o.x = (short)f2bf(f.x); o.y = (short)f2bf(f.y);
    o.z = (short)f2bf(f.z); o.w = (short)f2bf(f.w);
    *(short4*)dst = o;
    if (bid < 8) sums4[bid * 256 + tid] = float4{0.f, 0.f, 0.f, 0.f};
  } else {
    // Wv transpose: tile (by,bx) of Wv -> tile (bx,by) of wvT
    __shared__ short tls[64][65];
    const int t  = bid - 11264;
    const int bx = t & 15, by = t >> 4;
    const int r  = tid >> 4;            // 0..15
    const int c4 = (tid & 15) * 4;      // 0..60 step 4
#pragma unroll
    for (int s = 0; s < 4; ++s) {
      float4 f = *(const float4*)(Wv + (long long)(by * 64 + r + s * 16) * 1024 + bx * 64 + c4);
      tls[r + s * 16][c4 + 0] = (short)f2bf(f.x);
      tls[r + s * 16][c4 + 1] = (short)f2bf(f.y);
      tls[r + s * 16][c4 + 2] = (short)f2bf(f.z);
      tls[r + s * 16][c4 + 3] = (short)f2bf(f.w);
    }
    __syncthreads();
#pragma unroll
    for (int s = 0; s < 4; ++s) {
      const int a = r + s * 16;
      short4 o;
      o.x = tls[c4 + 0][a]; o.y = tls[c4 + 1][a];
      o.z = tls[c4 + 2][a]; o.w = tls[c4 + 3][a];
      *(short4*)(wvT + (long long)(bx * 64 + a) * 1024 + by * 64 + c4) = o;
    }
  }
}

// ---------------- m97-style GEMM: C = A(MxK) * B(NxK)^T, XCD-swizzled ------
// 1-D grid, id = x*ng + g, g=(y,z): blocks sharing an A-row-tile are
// congruent mod 8 -> same XCD -> A-reuse from its L2.
// LDS tiles XOR-swizzled (chunk c of row r at slot c^(r&7)): 0 bank conflicts.
// All modes except the QKV v-region use SWAPPED mfma operands so the acc tile
// is transposed: lane holds row = fr, cols = rb..rb+3 -> packed stores.
// MODE 1: bf16 output, row-major ldc (wvo = Wo*Wv precompute)
// MODE 2: merged QKVo. x<16: q/k row-major packed; x>=16: vo transposed
//         [b*4194304 + c*4096 + s] packed along s.
// MODE 4: QK^T + exp(scale*s) fused, bf16 packed stores, row-sum atomics.
// MODE 6: PV, 1/rowsum normalization, fp32 float4 stores (final output).
template <int MODE>
__global__ __launch_bounds__(256) void gemm_bt(const short* __restrict__ A,
                                               const short* __restrict__ B,
                                               void* __restrict__ Cv,
                                               float* __restrict__ sums,
                                               int K, int ldc, float scale,
                                               long long aStr, long long bStr,
                                               long long cStr, int gy, int ng) {
  __shared__ short lA[128 * 64];
  __shared__ short lB[128 * 64];
  const int bid = blockIdx.x;
  const int bx  = bid / ng;
  const int g   = bid % ng;
  const int by  = g % gy;
  const long long z = g / gy;
  const int tid = threadIdx.x;
  const int w   = tid >> 6;     // wave 0..3
  const int l   = tid & 63;     // lane
  const int wm  = w >> 1, wn = w & 1;
  const long long tm = (long long)by * 128;
  const long long tn = (long long)bx * 128;
  A += z * aStr;
  B += z * bStr;

  const bool swp = (MODE == 2) ? (bx < 16) : true;

  f32x4 acc[4][4] = {};

  const int lr   = l >> 3;                         // row-in-segment
  const int scw  = ((l & 7) ^ (lr & 7)) * 8;       // swizzled fetch chunk (shorts)
  const int q4   = l >> 4;                         // quad
  const int fr   = l & 15;                         // m (or n) within 16-tile
  const int xr   = fr & 7;                         // row-phase for read swizzle

  for (int k0 = 0; k0 < K; k0 += 64) {
#pragma unroll
    for (int t = 0; t < 4; ++t) {
      const int seg = w * 4 + t;
      gld_lds16(A + (tm + seg * 8 + lr) * (long long)K + k0 + scw, &lA[seg * 512]);
      gld_lds16(B + (tn + seg * 8 + lr) * (long long)K + k0 + scw, &lB[seg * 512]);
    }
    __syncthreads();
#pragma unroll
    for (int kk = 0; kk < 64; kk += 32) {
      const int cs = ((((kk >> 3)) + q4) ^ xr) << 3;   // swizzled chunk offset
      short8 af[4], bfr[4];
#pragma unroll
      for (int i = 0; i < 4; ++i)
        af[i] = *(const short8*)&lA[(wm * 64 + i * 16 + fr) * 64 + cs];
#pragma unroll
      for (int j = 0; j < 4; ++j)
        bfr[j] = *(const short8*)&lB[(wn * 64 + j * 16 + fr) * 64 + cs];
      if (swp) {
#pragma unroll
        for (int i = 0; i < 4; ++i)
#pragma unroll
          for (int j = 0; j < 4; ++j)
            acc[i][j] = __builtin_amdgcn_mfma_f32_16x16x32_bf16(bfr[j], af[i], acc[i][j], 0, 0, 0);
      } else {
#pragma unroll
        for (int i = 0; i < 4; ++i)
#pragma unroll
          for (int j = 0; j < 4; ++j)
            acc[i][j] = __builtin_amdgcn_mfma_f32_16x16x32_bf16(af[i], bfr[j], acc[i][j], 0, 0, 0);
      }
    }
    __syncthreads();
  }

  const int rb = (l >> 4) * 4;   // col base within 16-tile (swapped layout)

  if (MODE == 1) {
    unsigned short* dst = (unsigned short*)Cv + z * cStr;
#pragma unroll
    for (int i = 0; i < 4; ++i) {
      const long long row = tm + wm * 64 + i * 16 + fr;
#pragma unroll
      for (int j = 0; j < 4; ++j) {
        const long long colb = tn + wn * 64 + j * 16 + rb;
        short4 pk;
        pk.x = (short)f2bf(acc[i][j][0]); pk.y = (short)f2bf(acc[i][j][1]);
        pk.z = (short)f2bf(acc[i][j][2]); pk.w = (short)f2bf(acc[i][j][3]);
        *(short4*)(dst + row * ldc + colb) = pk;
      }
    }
  } else if (MODE == 2) {
    const int cb0 = (int)(tn & 1023) + wn * 64;
    if (swp) {
      const int region = (int)(tn >> 10);
      unsigned short* dst = (unsigned short*)Cv + (long long)region * 8388608ll;
#pragma unroll
      for (int i = 0; i < 4; ++i) {
        const long long row = tm + wm * 64 + i * 16 + fr;
#pragma unroll
        for (int j = 0; j < 4; ++j) {
          const int colb = cb0 + j * 16 + rb;
          short4 pk;
          pk.x = (short)f2bf(acc[i][j][0]); pk.y = (short)f2bf(acc[i][j][1]);
          pk.z = (short)f2bf(acc[i][j][2]); pk.w = (short)f2bf(acc[i][j][3]);
          *(short4*)(dst + row * 1024 + colb) = pk;
        }
      }
    } else {  // vo region: normal layout, pack along sequence dim
      unsigned short* dst = (unsigned short*)Cv + 16777216ll;
#pragma unroll
      for (int i = 0; i < 4; ++i)
#pragma unroll
        for (int j = 0; j < 4; ++j) {
          const long long row0 = tm + wm * 64 + i * 16 + rb;
          const long long b = row0 >> 12, s0 = row0 & 4095;
          const int c = cb0 + j * 16 + fr;
          short4 pk;
          pk.x = (short)f2bf(acc[i][j][0]); pk.y = (short)f2bf(acc[i][j][1]);
          pk.z = (short)f2bf(acc[i][j][2]); pk.w = (short)f2bf(acc[i][j][3]);
          *(short4*)(dst + b * 4194304ll + (long long)c * 4096 + s0) = pk;
        }
    }
  } else if (MODE == 4) {
    unsigned short* dst = (unsigned short*)Cv + z * cStr;
    float* sm = sums + z * 4096;
#pragma unroll
    for (int i = 0; i < 4; ++i) {
      const long long row = tm + wm * 64 + i * 16 + fr;
      float rs = 0.f;
#pragma unroll
      for (int j = 0; j < 4; ++j) {
        const long long colb = tn + wn * 64 + j * 16 + rb;
        short4 pk;
        float e0 = __expf(acc[i][j][0] * scale);
        float e1 = __expf(acc[i][j][1] * scale);
        float e2 = __expf(acc[i][j][2] * scale);
        float e3 = __expf(acc[i][j][3] * scale);
        rs += (e0 + e1) + (e2 + e3);
        pk.x = (short)f2bf(e0); pk.y = (short)f2bf(e1);
        pk.z = (short)f2bf(e2); pk.w = (short)f2bf(e3);
        *(short4*)(dst + row * ldc + colb) = pk;
      }
      rs += __shfl_xor(rs, 16);
      rs += __shfl_xor(rs, 32);
      if (l < 16) atomicAdd(sm + tm + wm * 64 + i * 16 + l, rs);
    }
  } else {  // MODE 6: fp32 normalized output
    float* dst = (float*)Cv + z * cStr;
    const float* sm = sums + z * 4096;
#pragma unroll
    for (int i = 0; i < 4; ++i) {
      const long long row = tm + wm * 64 + i * 16 + fr;
      const float inv = 1.0f / sm[row];
#pragma unroll
      for (int j = 0; j < 4; ++j) {
        const long long colb = tn + wn * 64 + j * 16 + rb;
        f32x4 o;
        o[0] = acc[i][j][0] * inv; o[1] = acc[i][j][1] * inv;
        o[2] = acc[i][j][2] * inv; o[3] = acc[i][j][3] * inv;
        *(f32x4*)(dst + row * ldc + colb) = o;
      }
    }
  }
}

// ---------------- launch ----------------
extern "C" void kernel_launch(void* const* d_in, const int* in_sizes, int n_in,
                              void* d_out, int out_size, void* d_ws, size_t ws_size,
                              hipStream_t stream) {
  const float* x  = (const float*)d_in[0];
  const float* Wq = (const float*)d_in[1];
  const float* Wk = (const float*)d_in[2];
  const float* Wv = (const float*)d_in[3];
  const float* Wo = (const float*)d_in[4];
  float* out = (float*)d_out;

  // ws layout (bytes):
  // [0,16M)    xb    8192x1024 bf16
  // [16M,22M)  wqkv  slot0=Wq, slot1=Wk, slot2=Wvo (=Wo*Wv, filled on device)
  // [22M,24M)  wo    1024x1024 bf16
  // [24M,40M)  q     [40M,56M) k      [56M,72M) vt[2][1024][4096] (= vo^T)
  // [72M,+32K) sums  8192 fp32 (zeroed in cast_all; region otherwise unused)
  // [88M,90M)  wvT   Wv^T bf16 (dead before QK writes sc over it)
  // [88M,152M) sc    2 x 4096x4096 bf16 scores (batched path)
  char* ws = (char*)d_ws;
  short* xb   = (short*)ws;
  short* wqkv = (short*)(ws + (16ll << 20));
  short* wo   = wqkv + 3145728;
  short* q    = (short*)(ws + (24ll << 20));
  short* k    = q + 8388608;
  short* vt   = q + 16777216;
  float* sums = (float*)(ws + (72ll << 20));
  short* wvT  = (short*)(ws + (88ll << 20));
  short* sc   = (short*)(ws + (88ll << 20));
  short* wvo  = wqkv + 2097152;

  const bool batched = ws_size >= 159383552ull;  // need 152 MiB
  dim3 blk(256);

  // merged casts + Wv transpose + zero sums: 11264 + 256 blocks
  cast_all<<<11520, blk, 0, stream>>>(x, Wq, Wk, Wv, Wo, xb, wqkv, wo, wvT,
                                      (float4*)sums);

  // Wvo = Wo * Wv  (= wo * wvT^T): M=N=K=1024, grid x=8, g=8
  gemm_bt<1><<<8 * 8, blk, 0, stream>>>(wo, wvT, wvo, nullptr, 1024, 1024, 1.f,
                                        0, 0, 0, 8, 8);

  // merged QKVo projection: M=8192, N=3072, K=1024; grid x=24, g=64
  gemm_bt<2><<<24 * 64, blk, 0, stream>>>(xb, wqkv, q, nullptr, 1024, 1024, 1.f,
                                          0, 0, 0, 64, 64);

  if (batched) {
    // QK^T + exp, both batches: x=32, g=(y32,z2)=64
    gemm_bt<4><<<32 * 64, blk, 0, stream>>>(q, k, sc, sums, 1024, 4096, 0.03125f,
                                            4194304ll, 4194304ll, 16777216ll, 32, 64);
    // P*vo + normalize -> d_out fp32, both batches: x=8, g=64
    gemm_bt<6><<<8 * 64, blk, 0, stream>>>(sc, vt, out, sums, 4096, 1024, 1.f,
                                           16777216ll, 4194304ll, 4194304ll, 32, 64);
  } else {
    for (int b = 0; b < 2; ++b) {
      short* qb  = q  + (long long)b * 4194304;
      short* kb  = k  + (long long)b * 4194304;
      short* vb  = vt + (long long)b * 4194304;
      float* ob  = out + (long long)b * 4194304;
      float* smb = sums + (long long)b * 4096;
      gemm_bt<4><<<32 * 32, blk, 0, stream>>>(qb, kb, sc, smb, 1024, 4096, 0.03125f,
                                              0, 0, 0, 32, 32);
      gemm_bt<6><<<8 * 32, blk, 0, stream>>>(sc, vb, ob, smb, 4096, 1024, 1.f,
                                             0, 0, 0, 32, 32);
    }
  }
}

// Round 8
// 318.470 us; speedup vs baseline: 1.6344x; 1.0953x over previous
//
#include <hip/hip_runtime.h>
#include <hip/hip_bf16.h>

// ---------------- helpers ----------------
using short8 = __attribute__((ext_vector_type(8))) short;
using f32x4  = __attribute__((ext_vector_type(4))) float;

__device__ __forceinline__ unsigned short f2bf(float f) {
  union { float f; unsigned int u; } x; x.f = f;
  unsigned int r = (x.u + 0x7fffu + ((x.u >> 16) & 1u)) >> 16;
  return (unsigned short)r;
}

__device__ __forceinline__ void gld_lds16(const short* gp, short* lp) {
  __builtin_amdgcn_global_load_lds((const __attribute__((address_space(1))) void*)gp,
                                   (__attribute__((address_space(3))) void*)lp, 16, 0, 0);
}

// ------- merged cast kernel -------------------------------------------------
// blocks [0,8192):      x -> xb (bf16, straight)
// blocks [8192,9216):   Wo -> U slot1 (straight)
// blocks [9216,9472):   Wq -> V slot0 (WqT, 64x64 LDS transpose)
// blocks [9472,9728):   Wk -> U slot0 (WkT)
// blocks [9728,9984):   Wv -> V slot1 (WvT)
// blocks [0,8):         also zero the 8192-float row-sum buffer (in ws).
__global__ __launch_bounds__(256) void cast_all(const float* __restrict__ x,
                                                const float* __restrict__ Wq,
                                                const float* __restrict__ Wk,
                                                const float* __restrict__ Wv,
                                                const float* __restrict__ Wo,
                                                short* __restrict__ xb,
                                                short* __restrict__ U,
                                                short* __restrict__ V,
                                                float4* __restrict__ sums4) {
  const int bid = blockIdx.x;
  const int tid = threadIdx.x;
  if (bid < 9216) {
    const float4* src;
    short* dst;
    const int i = bid * 256 + tid;
    if (bid < 8192) {
      src = (const float4*)x + i;
      dst = xb + 4ll * i;
    } else {
      const int off = i - 2097152;          // 0..262143 within Wo
      src = (const float4*)Wo + off;
      dst = U + 1048576 + 4ll * off;
    }
    float4 f = *src;
    short4 o;
    o.x = (short)f2bf(f.x); o.y = (short)f2bf(f.y);
    o.z = (short)f2bf(f.z); o.w = (short)f2bf(f.w);
    *(short4*)dst = o;
    if (bid < 8) sums4[bid * 256 + tid] = float4{0.f, 0.f, 0.f, 0.f};
  } else {
    // transpose: tile (by,bx) of W -> tile (bx,by) of dst
    __shared__ short tls[64][65];
    const int t  = bid - 9216;
    const int w  = t >> 8;                  // 0=Wq,1=Wk,2=Wv
    const int ti = t & 255;
    const int bx = ti & 15, by = ti >> 4;
    const float* src = (w == 0) ? Wq : (w == 1) ? Wk : Wv;
    short* dst = (w == 0) ? V : (w == 1) ? U : V + 1048576;
    const int r  = tid >> 4;                // 0..15
    const int c4 = (tid & 15) * 4;          // 0..60 step 4
#pragma unroll
    for (int s = 0; s < 4; ++s) {
      float4 f = *(const float4*)(src + (long long)(by * 64 + r + s * 16) * 1024 + bx * 64 + c4);
      tls[r + s * 16][c4 + 0] = (short)f2bf(f.x);
      tls[r + s * 16][c4 + 1] = (short)f2bf(f.y);
      tls[r + s * 16][c4 + 2] = (short)f2bf(f.z);
      tls[r + s * 16][c4 + 3] = (short)f2bf(f.w);
    }
    __syncthreads();
#pragma unroll
    for (int s = 0; s < 4; ++s) {
      const int a = r + s * 16;
      short4 o;
      o.x = tls[c4 + 0][a]; o.y = tls[c4 + 1][a];
      o.z = tls[c4 + 2][a]; o.w = tls[c4 + 3][a];
      *(short4*)(dst + (long long)(bx * 64 + a) * 1024 + by * 64 + c4) = o;
    }
  }
}

// ---------------- m97-style GEMM: C = A(MxK) * B(NxK)^T, XCD-swizzled ------
// 1-D grid, id = x*ng + g, g=(y,z): blocks sharing an A-row-tile are
// congruent mod 8 -> same XCD -> A-reuse from its L2.
// LDS tiles XOR-swizzled (chunk c of row r at slot c^(r&7)): 0 bank conflicts.
// Swapped mfma operands (except vo region): lane holds row=fr, cols rb..rb+3
// -> packed stores.
// MODE 1: bf16 row-major, z-batched (small weight-product GEMMs)
// MODE 2: merged t/vo projection. bx<8: t row-major; bx>=8: vo transposed
//         into vt=Cv+8388608: [b*4194304 + c*4096 + s], packed along s.
// MODE 4: QK^T + exp(scale*s) fused, bf16 packed stores, row-sum atomics.
// MODE 6: PV, 1/rowsum normalization, fp32 float4 stores (final output).
template <int MODE>
__global__ __launch_bounds__(256) void gemm_bt(const short* __restrict__ A,
                                               const short* __restrict__ B,
                                               void* __restrict__ Cv,
                                               float* __restrict__ sums,
                                               int K, int ldc, float scale,
                                               long long aStr, long long bStr,
                                               long long cStr, int gy, int ng) {
  __shared__ short lA[128 * 64];
  __shared__ short lB[128 * 64];
  const int bid = blockIdx.x;
  const int bx  = bid / ng;
  const int g   = bid % ng;
  const int by  = g % gy;
  const long long z = g / gy;
  const int tid = threadIdx.x;
  const int w   = tid >> 6;     // wave 0..3
  const int l   = tid & 63;     // lane
  const int wm  = w >> 1, wn = w & 1;
  const long long tm = (long long)by * 128;
  const long long tn = (long long)bx * 128;
  A += z * aStr;
  B += z * bStr;

  const bool swp = (MODE == 2) ? (bx < 8) : true;

  f32x4 acc[4][4] = {};

  const int lr   = l >> 3;                         // row-in-segment
  const int scw  = ((l & 7) ^ (lr & 7)) * 8;       // swizzled fetch chunk (shorts)
  const int q4   = l >> 4;                         // quad
  const int fr   = l & 15;                         // m (or n) within 16-tile
  const int xr   = fr & 7;                         // row-phase for read swizzle

  for (int k0 = 0; k0 < K; k0 += 64) {
#pragma unroll
    for (int t = 0; t < 4; ++t) {
      const int seg = w * 4 + t;
      gld_lds16(A + (tm + seg * 8 + lr) * (long long)K + k0 + scw, &lA[seg * 512]);
      gld_lds16(B + (tn + seg * 8 + lr) * (long long)K + k0 + scw, &lB[seg * 512]);
    }
    __syncthreads();
#pragma unroll
    for (int kk = 0; kk < 64; kk += 32) {
      const int cs = ((((kk >> 3)) + q4) ^ xr) << 3;   // swizzled chunk offset
      short8 af[4], bfr[4];
#pragma unroll
      for (int i = 0; i < 4; ++i)
        af[i] = *(const short8*)&lA[(wm * 64 + i * 16 + fr) * 64 + cs];
#pragma unroll
      for (int j = 0; j < 4; ++j)
        bfr[j] = *(const short8*)&lB[(wn * 64 + j * 16 + fr) * 64 + cs];
      if (swp) {
#pragma unroll
        for (int i = 0; i < 4; ++i)
#pragma unroll
          for (int j = 0; j < 4; ++j)
            acc[i][j] = __builtin_amdgcn_mfma_f32_16x16x32_bf16(bfr[j], af[i], acc[i][j], 0, 0, 0);
      } else {
#pragma unroll
        for (int i = 0; i < 4; ++i)
#pragma unroll
          for (int j = 0; j < 4; ++j)
            acc[i][j] = __builtin_amdgcn_mfma_f32_16x16x32_bf16(af[i], bfr[j], acc[i][j], 0, 0, 0);
      }
    }
    __syncthreads();
  }

  const int rb = (l >> 4) * 4;   // col base within 16-tile (swapped layout)

  if (MODE == 1) {
    unsigned short* dst = (unsigned short*)Cv + z * cStr;
#pragma unroll
    for (int i = 0; i < 4; ++i) {
      const long long row = tm + wm * 64 + i * 16 + fr;
#pragma unroll
      for (int j = 0; j < 4; ++j) {
        const long long colb = tn + wn * 64 + j * 16 + rb;
        short4 pk;
        pk.x = (short)f2bf(acc[i][j][0]); pk.y = (short)f2bf(acc[i][j][1]);
        pk.z = (short)f2bf(acc[i][j][2]); pk.w = (short)f2bf(acc[i][j][3]);
        *(short4*)(dst + row * ldc + colb) = pk;
      }
    }
  } else if (MODE == 2) {
    if (swp) {   // t region: row-major, packed
      unsigned short* dst = (unsigned short*)Cv;
      const int cb0 = (int)tn + wn * 64;
#pragma unroll
      for (int i = 0; i < 4; ++i) {
        const long long row = tm + wm * 64 + i * 16 + fr;
#pragma unroll
        for (int j = 0; j < 4; ++j) {
          const int colb = cb0 + j * 16 + rb;
          short4 pk;
          pk.x = (short)f2bf(acc[i][j][0]); pk.y = (short)f2bf(acc[i][j][1]);
          pk.z = (short)f2bf(acc[i][j][2]); pk.w = (short)f2bf(acc[i][j][3]);
          *(short4*)(dst + row * 1024 + colb) = pk;
        }
      }
    } else {     // vo region: normal layout, pack along sequence dim
      unsigned short* dst = (unsigned short*)Cv + 8388608ll;
      const int cb0 = (int)(tn - 1024) + wn * 64;
#pragma unroll
      for (int i = 0; i < 4; ++i)
#pragma unroll
        for (int j = 0; j < 4; ++j) {
          const long long row0 = tm + wm * 64 + i * 16 + rb;
          const long long b = row0 >> 12, s0 = row0 & 4095;
          const int c = cb0 + j * 16 + fr;
          short4 pk;
          pk.x = (short)f2bf(acc[i][j][0]); pk.y = (short)f2bf(acc[i][j][1]);
          pk.z = (short)f2bf(acc[i][j][2]); pk.w = (short)f2bf(acc[i][j][3]);
          *(short4*)(dst + b * 4194304ll + (long long)c * 4096 + s0) = pk;
        }
    }
  } else if (MODE == 4) {
    unsigned short* dst = (unsigned short*)Cv + z * cStr;
    float* sm = sums + z * 4096;
#pragma unroll
    for (int i = 0; i < 4; ++i) {
      const long long row = tm + wm * 64 + i * 16 + fr;
      float rs = 0.f;
#pragma unroll
      for (int j = 0; j < 4; ++j) {
        const long long colb = tn + wn * 64 + j * 16 + rb;
        short4 pk;
        float e0 = __expf(acc[i][j][0] * scale);
        float e1 = __expf(acc[i][j][1] * scale);
        float e2 = __expf(acc[i][j][2] * scale);
        float e3 = __expf(acc[i][j][3] * scale);
        rs += (e0 + e1) + (e2 + e3);
        pk.x = (short)f2bf(e0); pk.y = (short)f2bf(e1);
        pk.z = (short)f2bf(e2); pk.w = (short)f2bf(e3);
        *(short4*)(dst + row * ldc + colb) = pk;
      }
      rs += __shfl_xor(rs, 16);
      rs += __shfl_xor(rs, 32);
      if (l < 16) atomicAdd(sm + tm + wm * 64 + i * 16 + l, rs);
    }
  } else {  // MODE 6: fp32 normalized output
    float* dst = (float*)Cv + z * cStr;
    const float* sm = sums + z * 4096;
#pragma unroll
    for (int i = 0; i < 4; ++i) {
      const long long row = tm + wm * 64 + i * 16 + fr;
      const float inv = 1.0f / sm[row];
#pragma unroll
      for (int j = 0; j < 4; ++j) {
        const long long colb = tn + wn * 64 + j * 16 + rb;
        f32x4 o;
        o[0] = acc[i][j][0] * inv; o[1] = acc[i][j][1] * inv;
        o[2] = acc[i][j][2] * inv; o[3] = acc[i][j][3] * inv;
        *(f32x4*)(dst + row * ldc + colb) = o;
      }
    }
  }
}

// ---------------- launch ----------------
extern "C" void kernel_launch(void* const* d_in, const int* in_sizes, int n_in,
                              void* d_out, int out_size, void* d_ws, size_t ws_size,
                              hipStream_t stream) {
  const float* x  = (const float*)d_in[0];
  const float* Wq = (const float*)d_in[1];
  const float* Wk = (const float*)d_in[2];
  const float* Wv = (const float*)d_in[3];
  const float* Wo = (const float*)d_in[4];
  float* out = (float*)d_out;

  // Algebra: scores = x·(Wq^T·Wk)·x^T, out = P_norm·x·(Wo·Wv)^T.
  // W2 slice0 = Wqk^T = Wk^T·Wq  (B operand for t = x·Wqk)
  // W2 slice1 = Wvo   = Wo·Wv    (B operand for vo = x·Wvo^T)
  // Small GEMM z-batch: U=[WkT; Wo], V=[WqT; WvT], C_z = U_z·V_z^T.
  //
  // ws layout (bytes):
  // [0,16M)    xb   8192x1024 bf16 (alive through QK: scores B operand)
  // [16M,20M)  U    [WkT; Wo]      [20M,24M) V [WqT; WvT]
  // [24M,28M)  W2   [WqkT; Wvo]
  // [28M,44M)  t    8192x1024 bf16  [44M,60M) vt[2][1024][4096] (vo^T)
  // [60M,+32K) sums 8192 fp32 (zeroed in cast_all)
  // [88M,152M) sc   2 x 4096x4096 bf16 scores (batched path)
  char* ws = (char*)d_ws;
  short* xb = (short*)ws;
  short* U  = (short*)(ws + (16ll << 20));
  short* V  = (short*)(ws + (20ll << 20));
  short* W2 = (short*)(ws + (24ll << 20));
  short* t  = (short*)(ws + (28ll << 20));
  short* vt = t + 8388608;
  float* sums = (float*)(ws + (60ll << 20));
  short* sc = (short*)(ws + (88ll << 20));

  const bool batched = ws_size >= 159383552ull;  // need 152 MiB
  dim3 blk(256);

  // casts + 3 weight transposes + zero sums: 8192+1024+768 = 9984 blocks
  cast_all<<<9984, blk, 0, stream>>>(x, Wq, Wk, Wv, Wo, xb, U, V, (float4*)sums);

  // W2 = [WkT·WqT^T ; Wo·WvT^T], z=2: M=N=K=1024, grid x=8, g=(y8,z2)=16
  gemm_bt<1><<<8 * 16, blk, 0, stream>>>(U, V, W2, nullptr, 1024, 1024, 1.f,
                                         1048576ll, 1048576ll, 1048576ll, 8, 16);

  // merged t/vo projection: M=8192, N=2048, K=1024; grid x=16, g=64
  gemm_bt<2><<<16 * 64, blk, 0, stream>>>(xb, W2, t, nullptr, 1024, 1024, 1.f,
                                          0, 0, 0, 64, 64);

  if (batched) {
    // scores = t·xb^T + exp, both batches: x=32, g=(y32,z2)=64
    gemm_bt<4><<<32 * 64, blk, 0, stream>>>(t, xb, sc, sums, 1024, 4096, 0.03125f,
                                            4194304ll, 4194304ll, 16777216ll, 32, 64);
    // P·vo + normalize -> d_out fp32, both batches: x=8, g=64
    gemm_bt<6><<<8 * 64, blk, 0, stream>>>(sc, vt, out, sums, 4096, 1024, 1.f,
                                           16777216ll, 4194304ll, 4194304ll, 32, 64);
  } else {
    for (int b = 0; b < 2; ++b) {
      short* tb  = t  + (long long)b * 4194304;
      short* xbb = xb + (long long)b * 4194304;
      short* vb  = vt + (long long)b * 4194304;
      float* ob  = out + (long long)b * 4194304;
      float* smb = sums + (long long)b * 4096;
      gemm_bt<4><<<32 * 32, blk, 0, stream>>>(tb, xbb, sc, smb, 1024, 4096, 0.03125f,
                                              0, 0, 0, 32, 32);
      gemm_bt<6><<<8 * 32, blk, 0, stream>>>(sc, vb, ob, smb, 4096, 1024, 1.f,
                                             0, 0, 0, 32, 32);
    }
  }
}